// Round 1
// 505.843 us; speedup vs baseline: 1.0517x; 1.0517x over previous
//
#include <hip/hip_runtime.h>
#include <math.h>

#define BB 64
#define TT 200
#define NUMQ 1000
#define DIMS 128
#define SIZEM 50
#define NROWS (BB*TT)   // 12800
#define NCH 8
#define CL  25          // TT / NCH

// ---------------- K1: k = k_emb[q] + pid_emb[pid] ----------------
__global__ __launch_bounds__(256) void k_kernel(
    const int* __restrict__ qv, const int* __restrict__ pidv,
    const float* __restrict__ k_emb, const float* __restrict__ pid_emb,
    float* __restrict__ kout)
{
    int i = blockIdx.x * 256 + threadIdx.x;   // over NROWS*32 float4s
    int row = i >> 5;
    int d4  = i & 31;
    int qq = qv[row];
    int pp = pidv[row];
    float4 kvv = ((const float4*)(k_emb  + (size_t)qq * DIMS))[d4];
    float4 pvv = ((const float4*)(pid_emb + (size_t)pp * DIMS))[d4];
    float4 o;
    o.x = kvv.x + pvv.x; o.y = kvv.y + pvv.y;
    o.z = kvv.z + pvv.z; o.w = kvv.w + pvv.w;
    ((float4*)kout)[i] = o;
}

// ---------------- K2: w = softmax(k @ Mk^T) over m=50 ----------------
// 4 rows per wave (independent fma chains = ILP); row base forced wave-uniform
// via readfirstlane so k-row reads become s_load batches, not per-d broadcast
// global_load_dword (the old version's hidden latency bottleneck at 1 wave/SIMD).
__global__ __launch_bounds__(256) void w_kernel(
    const float* __restrict__ k, const float* __restrict__ Mk,
    float* __restrict__ wout)
{
    __shared__ float MkT[DIMS * SIZEM];    // MkT[d*50+m]
    int tid = threadIdx.x;
    for (int idx = tid; idx < SIZEM * DIMS; idx += 256) {
        int m = idx >> 7;           // Mk row-major (50,128)
        int d = idx & 127;
        MkT[d * SIZEM + m] = Mk[idx];
    }
    __syncthreads();

    int wave = tid >> 6;
    int lane = tid & 63;
    int m = (lane < SIZEM) ? lane : (SIZEM - 1);
    int g = blockIdx.x * 4 + wave;          // group id 0..3199, 4 rows each

    int row0 = __builtin_amdgcn_readfirstlane(g * 4);   // wave-uniform -> s_load
    const float* k0 = k + (size_t)row0 * DIMS;

    float a0 = 0.f, a1 = 0.f, a2 = 0.f, a3 = 0.f;
    #pragma unroll 8
    for (int d = 0; d < DIMS; d++) {
        float mk = MkT[d * SIZEM + m];
        a0 = fmaf(k0[d],            mk, a0);
        a1 = fmaf(k0[DIMS + d],     mk, a1);
        a2 = fmaf(k0[2 * DIMS + d], mk, a2);
        a3 = fmaf(k0[3 * DIMS + d], mk, a3);
    }

    #define SOFTMAX_STORE(ACC, RI) { \
        float val = (lane < SIZEM) ? (ACC) : -INFINITY; \
        _Pragma("unroll") \
        for (int off = 32; off >= 1; off >>= 1) \
            val = fmaxf(val, __shfl_xor(val, off)); \
        float ex = (lane < SIZEM) ? __expf((ACC) - val) : 0.f; \
        float ss = ex; \
        _Pragma("unroll") \
        for (int off = 32; off >= 1; off >>= 1) \
            ss += __shfl_xor(ss, off); \
        if (lane < SIZEM) \
            wout[(size_t)(row0 + (RI)) * SIZEM + lane] = ex / ss; }

    SOFTMAX_STORE(a0, 0)
    SOFTMAX_STORE(a1, 1)
    SOFTMAX_STORE(a2, 2)
    SOFTMAX_STORE(a3, 3)
    #undef SOFTMAX_STORE
}

// ---------------- K3: e = sigmoid(v@e_W^T+e_b), a = tanh(v@a_W^T+a_b) ----------------
__global__ __launch_bounds__(256) void ea_kernel(
    const int* __restrict__ qv, const int* __restrict__ rv, const int* __restrict__ pidv,
    const float* __restrict__ v_emb, const float* __restrict__ pid_emb,
    const float* __restrict__ e_W, const float* __restrict__ e_b,
    const float* __restrict__ a_W, const float* __restrict__ a_b,
    float* __restrict__ e_out, float* __restrict__ a_out)
{
    __shared__ float vb[32][DIMS];   // 16 KB
    int tid = threadIdx.x;
    int o   = tid & 127;
    int sel = tid >> 7;              // 0 = e, 1 = a (wave-uniform)
    int r0  = blockIdx.x * 32;       // grid 400

    for (int idx = tid; idx < 32 * DIMS; idx += 256) {
        int r = idx >> 7, d = idx & 127;
        int row = r0 + r;
        int x = qv[row] + NUMQ * rv[row];
        vb[r][d] = v_emb[(size_t)x * DIMS + d] + pid_emb[(size_t)pidv[row] * DIMS + d];
    }
    __syncthreads();

    float acc[32];
    #pragma unroll
    for (int r = 0; r < 32; r++) acc[r] = 0.f;

    const float* W = sel ? a_W : e_W;
    const float* wrow = W + (size_t)o * DIMS;
    for (int d = 0; d < DIMS; d += 4) {
        float4 wv = *(const float4*)(wrow + d);
        #pragma unroll
        for (int r = 0; r < 32; r++) {
            float4 v4 = *(const float4*)(&vb[r][d]);
            acc[r] = fmaf(v4.x, wv.x, acc[r]);
            acc[r] = fmaf(v4.y, wv.y, acc[r]);
            acc[r] = fmaf(v4.z, wv.z, acc[r]);
            acc[r] = fmaf(v4.w, wv.w, acc[r]);
        }
    }
    float bo = sel ? a_b[o] : e_b[o];
    float* outp = sel ? a_out : e_out;
    #pragma unroll
    for (int r = 0; r < 32; r++) {
        float x = acc[r] + bo;
        float y = sel ? tanhf(x) : 1.f / (1.f + __expf(-x));
        outp[(size_t)(r0 + r) * DIMS + o] = y;
    }
}

// ---------------- S1: per-chunk affine composition (A,B) over 25 steps ----------------
// s_{t+1} = alpha*s + beta, alpha = 1 - w*e, beta = w*a
// chunk map: A *= alpha ; B = alpha*B + beta
__global__ __launch_bounds__(128) void compose_kernel(
    const float* __restrict__ w, const float* __restrict__ e, const float* __restrict__ a,
    float* __restrict__ Abuf, float* __restrict__ Bbuf)
{
    int b = blockIdx.x >> 3;        // grid 512 = 64 b x 8 chunks
    int c = blockIdx.x & 7;
    int d = threadIdx.x;            // 128

    float A[SIZEM], Bv[SIZEM];
    #pragma unroll
    for (int m = 0; m < SIZEM; m++) { A[m] = 1.f; Bv[m] = 0.f; }

    const float* wr = w + ((size_t)b * TT + c * CL) * SIZEM;
    const float* er = e + ((size_t)b * TT + c * CL) * DIMS + d;
    const float* ar = a + ((size_t)b * TT + c * CL) * DIMS + d;

    for (int t = 0; t < CL; t++) {
        float ed = er[(size_t)t * DIMS];
        float ad = ar[(size_t)t * DIMS];
        const float* wt = wr + (size_t)t * SIZEM;
        #pragma unroll
        for (int m = 0; m < SIZEM; m++) {
            float wv = wt[m];                       // block-uniform -> s_load
            float t1 = wv * ed;
            A[m]  = fmaf(-A[m], t1, A[m]);          // A *= (1 - t1)
            Bv[m] = fmaf(-Bv[m], t1, fmaf(wv, ad, Bv[m]));
        }
    }
    float* Ao = Abuf + ((size_t)b * NCH + c) * SIZEM * DIMS + d;
    float* Bo = Bbuf + ((size_t)b * NCH + c) * SIZEM * DIMS + d;
    #pragma unroll
    for (int m = 0; m < SIZEM; m++) {
        Ao[(size_t)m * DIMS] = A[m];
        Bo[(size_t)m * DIMS] = Bv[m];
    }
}

// ---------------- S3: prefix-scan chunk start in-block, then expand ----------------
// Replaces boundary_kernel + s_start round-trip: each (b,c) block composes its own
// chunk-start state from A/B of chunks 0..c-1 (identical fmaf sequence => bitwise
// same result), then streams Mv and computes read in-register.
__global__ __launch_bounds__(128) void expand_kernel(
    const float* __restrict__ w, const float* __restrict__ e, const float* __restrict__ a,
    const float* __restrict__ Abuf, const float* __restrict__ Bbuf,
    const float* __restrict__ Mv0,
    float* __restrict__ mv_out,     // [B][201][50][128]
    float* __restrict__ read_out)   // [NROWS][128]
{
    int b = blockIdx.x >> 3;        // grid 512 = 64 b x 8 chunks
    int c = blockIdx.x & 7;
    int d = threadIdx.x;            // 128

    float s[SIZEM];
    #pragma unroll
    for (int m = 0; m < SIZEM; m++) s[m] = Mv0[(size_t)m * DIMS + d];

    for (int cc = 0; cc < c; cc++) {            // c is block-uniform
        const float* Ao = Abuf + ((size_t)b * NCH + cc) * (SIZEM * DIMS) + d;
        const float* Bo = Bbuf + ((size_t)b * NCH + cc) * (SIZEM * DIMS) + d;
        #pragma unroll
        for (int m = 0; m < SIZEM; m++)
            s[m] = fmaf(Ao[(size_t)m * DIMS], s[m], Bo[(size_t)m * DIMS]);
    }

    float* mvb = mv_out + (size_t)b * (TT + 1) * SIZEM * DIMS;
    if (c == 0) {
        #pragma unroll
        for (int m = 0; m < SIZEM; m++)
            mvb[(size_t)m * DIMS + d] = s[m];       // Mv[:,0] = Mv0
    }

    const float* wr = w + ((size_t)b * TT + c * CL) * SIZEM;
    const float* er = e + ((size_t)b * TT + c * CL) * DIMS + d;
    const float* ar = a + ((size_t)b * TT + c * CL) * DIMS + d;
    float*       rr = read_out + ((size_t)b * TT + c * CL) * DIMS + d;

    float ed = er[0];
    float ad = ar[0];
    for (int t = 0; t < CL; t++) {
        // prefetch next step's e/a before issuing this step's stores
        int tn = (t + 1 < CL) ? t + 1 : t;
        float edn = er[(size_t)tn * DIMS];
        float adn = ar[(size_t)tn * DIMS];

        const float* wt = wr + (size_t)t * SIZEM;   // block-uniform row -> s_load
        float* mvt = mvb + (size_t)(c * CL + t + 1) * SIZEM * DIMS + d;
        float pr = 0.f;
        #pragma unroll
        for (int m = 0; m < SIZEM; m++) {
            float wv = wt[m];
            pr = fmaf(wv, s[m], pr);                // read uses pre-update state
            float t1 = wv * ed;
            s[m] = fmaf(-s[m], t1, fmaf(wv, ad, s[m]));
            mvt[(size_t)m * DIMS] = s[m];
        }
        rr[(size_t)t * DIMS] = pr;
        ed = edn; ad = adn;
    }
}

// ---------------- K5: f = tanh([read,k]@f_W^T + f_b); p = sigmoid(f@p_W^T + p_b) ----------------
__global__ __launch_bounds__(256) void fp_kernel(
    const float* __restrict__ readb, const float* __restrict__ k,
    const float* __restrict__ f_W, const float* __restrict__ f_b,
    const float* __restrict__ p_W, const float* __restrict__ p_b,
    float* __restrict__ p_out)
{
    __shared__ float rk[32][256];    // 32 KB
    __shared__ float pred[4][16];
    int tid = threadIdx.x;
    int o  = tid & 127;
    int rh = tid >> 7;               // rows 0..15 / 16..31
    int r0 = blockIdx.x * 32;        // grid 400

    for (int idx = tid; idx < 32 * 256; idx += 256) {
        int r = idx >> 8, dd = idx & 255;
        size_t row = (size_t)(r0 + r);
        rk[r][dd] = (dd < 128) ? readb[row * 128 + dd] : k[row * 128 + (dd - 128)];
    }
    __syncthreads();

    float acc[16];
    #pragma unroll
    for (int i = 0; i < 16; i++) acc[i] = 0.f;

    const float* wrow = f_W + (size_t)o * 256;
    for (int dd = 0; dd < 256; dd += 4) {
        float4 wv = *(const float4*)(wrow + dd);
        #pragma unroll
        for (int i = 0; i < 16; i++) {
            int r = rh * 16 + i;
            float4 v4 = *(const float4*)(&rk[r][dd]);
            acc[i] = fmaf(v4.x, wv.x, acc[i]);
            acc[i] = fmaf(v4.y, wv.y, acc[i]);
            acc[i] = fmaf(v4.z, wv.z, acc[i]);
            acc[i] = fmaf(v4.w, wv.w, acc[i]);
        }
    }

    int wave = tid >> 6;
    float fb = f_b[o];
    float pw = p_W[o];
    float pb = p_b[0];
    #pragma unroll
    for (int i = 0; i < 16; i++) {
        float fv = tanhf(acc[i] + fb);
        float v = fv * pw;
        #pragma unroll
        for (int off = 32; off >= 1; off >>= 1)
            v += __shfl_xor(v, off);
        if ((tid & 63) == 0) pred[wave][i] = v;
    }
    __syncthreads();
    if (tid < 32) {
        int h = tid >> 4, ri = tid & 15;
        float sum = pred[2 * h][ri] + pred[2 * h + 1][ri];
        p_out[r0 + tid] = 1.f / (1.f + __expf(-(sum + pb)));
    }
}

extern "C" void kernel_launch(void* const* d_in, const int* in_sizes, int n_in,
                              void* d_out, int out_size, void* d_ws, size_t ws_size,
                              hipStream_t stream) {
    const int*   qv      = (const int*)d_in[0];
    const int*   rv      = (const int*)d_in[1];
    const int*   pidv    = (const int*)d_in[2];
    const float* pid_emb = (const float*)d_in[3];
    const float* k_emb   = (const float*)d_in[4];
    const float* v_emb   = (const float*)d_in[5];
    const float* Mk      = (const float*)d_in[6];
    const float* Mv0     = (const float*)d_in[7];
    const float* f_W     = (const float*)d_in[8];
    const float* f_b     = (const float*)d_in[9];
    const float* p_W     = (const float*)d_in[10];
    const float* p_b     = (const float*)d_in[11];
    const float* e_W     = (const float*)d_in[12];
    const float* e_b     = (const float*)d_in[13];
    const float* a_W     = (const float*)d_in[14];
    const float* a_b     = (const float*)d_in[15];

    float* out    = (float*)d_out;
    float* p_out  = out;                 // 12800
    float* mv_out = out + NROWS;         // 64*201*50*128

    float* ws = (float*)d_ws;
    float* k_buf    = ws;                          // 1,638,400
    float* w_buf    = ws +  1638400;               //   640,000
    float* e_buf    = ws +  2278400;               // 1,638,400
    float* a_buf    = ws +  3916800;               // 1,638,400
    float* read_buf = ws +  5555200;               // 1,638,400
    float* A_buf    = ws +  7193600;               // 3,276,800
    float* B_buf    = ws + 10470400;               // 3,276,800  (total 55 MB)

    k_kernel<<<NROWS * 32 / 256, 256, 0, stream>>>(qv, pidv, k_emb, pid_emb, k_buf);
    w_kernel<<<800, 256, 0, stream>>>(k_buf, Mk, w_buf);
    ea_kernel<<<NROWS / 32, 256, 0, stream>>>(qv, rv, pidv, v_emb, pid_emb,
                                              e_W, e_b, a_W, a_b, e_buf, a_buf);
    compose_kernel<<<BB * NCH, 128, 0, stream>>>(w_buf, e_buf, a_buf, A_buf, B_buf);
    expand_kernel<<<BB * NCH, 128, 0, stream>>>(w_buf, e_buf, a_buf, A_buf, B_buf,
                                                Mv0, mv_out, read_buf);
    fp_kernel<<<NROWS / 32, 256, 0, stream>>>(read_buf, k_buf, f_W, f_b, p_W, p_b, p_out);
}

// Round 2
// 487.430 us; speedup vs baseline: 1.0914x; 1.0378x over previous
//
#include <hip/hip_runtime.h>
#include <math.h>

#define BB 64
#define TT 200
#define NUMQ 1000
#define DIMS 128
#define SIZEM 50
#define NROWS (BB*TT)   // 12800
#define NCH 8
#define CL  25          // TT / NCH

// ---------------- K1: k = k_emb[q] + pid_emb[pid] ----------------
__global__ __launch_bounds__(256) void k_kernel(
    const int* __restrict__ qv, const int* __restrict__ pidv,
    const float* __restrict__ k_emb, const float* __restrict__ pid_emb,
    float* __restrict__ kout)
{
    int i = blockIdx.x * 256 + threadIdx.x;   // over NROWS*32 float4s
    int row = i >> 5;
    int d4  = i & 31;
    int qq = qv[row];
    int pp = pidv[row];
    float4 kvv = ((const float4*)(k_emb  + (size_t)qq * DIMS))[d4];
    float4 pvv = ((const float4*)(pid_emb + (size_t)pp * DIMS))[d4];
    float4 o;
    o.x = kvv.x + pvv.x; o.y = kvv.y + pvv.y;
    o.z = kvv.z + pvv.z; o.w = kvv.w + pvv.w;
    ((float4*)kout)[i] = o;
}

// ---------------- K2: w = softmax(k @ Mk^T) over m=50 ----------------
// 4 rows per wave (independent fma chains = ILP); row base forced wave-uniform
// via readfirstlane so k-row reads become s_load batches.
__global__ __launch_bounds__(256) void w_kernel(
    const float* __restrict__ k, const float* __restrict__ Mk,
    float* __restrict__ wout)
{
    __shared__ float MkT[DIMS * SIZEM];    // MkT[d*50+m]
    int tid = threadIdx.x;
    for (int idx = tid; idx < SIZEM * DIMS; idx += 256) {
        int m = idx >> 7;           // Mk row-major (50,128)
        int d = idx & 127;
        MkT[d * SIZEM + m] = Mk[idx];
    }
    __syncthreads();

    int wave = tid >> 6;
    int lane = tid & 63;
    int m = (lane < SIZEM) ? lane : (SIZEM - 1);
    int g = blockIdx.x * 4 + wave;          // group id 0..3199, 4 rows each

    int row0 = __builtin_amdgcn_readfirstlane(g * 4);   // wave-uniform -> s_load
    const float* k0 = k + (size_t)row0 * DIMS;

    float a0 = 0.f, a1 = 0.f, a2 = 0.f, a3 = 0.f;
    #pragma unroll 8
    for (int d = 0; d < DIMS; d++) {
        float mk = MkT[d * SIZEM + m];
        a0 = fmaf(k0[d],            mk, a0);
        a1 = fmaf(k0[DIMS + d],     mk, a1);
        a2 = fmaf(k0[2 * DIMS + d], mk, a2);
        a3 = fmaf(k0[3 * DIMS + d], mk, a3);
    }

    #define SOFTMAX_STORE(ACC, RI) { \
        float val = (lane < SIZEM) ? (ACC) : -INFINITY; \
        _Pragma("unroll") \
        for (int off = 32; off >= 1; off >>= 1) \
            val = fmaxf(val, __shfl_xor(val, off)); \
        float ex = (lane < SIZEM) ? __expf((ACC) - val) : 0.f; \
        float ss = ex; \
        _Pragma("unroll") \
        for (int off = 32; off >= 1; off >>= 1) \
            ss += __shfl_xor(ss, off); \
        if (lane < SIZEM) \
            wout[(size_t)(row0 + (RI)) * SIZEM + lane] = ex / ss; }

    SOFTMAX_STORE(a0, 0)
    SOFTMAX_STORE(a1, 1)
    SOFTMAX_STORE(a2, 2)
    SOFTMAX_STORE(a3, 3)
    #undef SOFTMAX_STORE
}

// ---------------- K3: e = sigmoid(v@e_W^T+e_b), a = tanh(v@a_W^T+a_b) ----------------
__global__ __launch_bounds__(256) void ea_kernel(
    const int* __restrict__ qv, const int* __restrict__ rv, const int* __restrict__ pidv,
    const float* __restrict__ v_emb, const float* __restrict__ pid_emb,
    const float* __restrict__ e_W, const float* __restrict__ e_b,
    const float* __restrict__ a_W, const float* __restrict__ a_b,
    float* __restrict__ e_out, float* __restrict__ a_out)
{
    __shared__ float vb[32][DIMS];   // 16 KB
    int tid = threadIdx.x;
    int o   = tid & 127;
    int sel = tid >> 7;              // 0 = e, 1 = a (wave-uniform)
    int r0  = blockIdx.x * 32;       // grid 400

    for (int idx = tid; idx < 32 * DIMS; idx += 256) {
        int r = idx >> 7, d = idx & 127;
        int row = r0 + r;
        int x = qv[row] + NUMQ * rv[row];
        vb[r][d] = v_emb[(size_t)x * DIMS + d] + pid_emb[(size_t)pidv[row] * DIMS + d];
    }
    __syncthreads();

    float acc[32];
    #pragma unroll
    for (int r = 0; r < 32; r++) acc[r] = 0.f;

    const float* W = sel ? a_W : e_W;
    const float* wrow = W + (size_t)o * DIMS;
    for (int d = 0; d < DIMS; d += 4) {
        float4 wv = *(const float4*)(wrow + d);
        #pragma unroll
        for (int r = 0; r < 32; r++) {
            float4 v4 = *(const float4*)(&vb[r][d]);
            acc[r] = fmaf(v4.x, wv.x, acc[r]);
            acc[r] = fmaf(v4.y, wv.y, acc[r]);
            acc[r] = fmaf(v4.z, wv.z, acc[r]);
            acc[r] = fmaf(v4.w, wv.w, acc[r]);
        }
    }
    float bo = sel ? a_b[o] : e_b[o];
    float* outp = sel ? a_out : e_out;
    #pragma unroll
    for (int r = 0; r < 32; r++) {
        float x = acc[r] + bo;
        float y = sel ? tanhf(x) : 1.f / (1.f + __expf(-x));
        outp[(size_t)(r0 + r) * DIMS + o] = y;
    }
}

// ---------------- S1: per-chunk affine composition (A,B) over 25 steps ----------------
// s_{t+1} = alpha*s + beta, alpha = 1 - w*e, beta = w*a
// chunk map: A *= alpha ; B = alpha*B + beta
// Block map c*64+b: all 8 chunks of batch b land on XCD b%8 so expand's
// A/B + e/a/w reads hit that XCD's L2.
__global__ __launch_bounds__(128) void compose_kernel(
    const float* __restrict__ w, const float* __restrict__ e, const float* __restrict__ a,
    float* __restrict__ Abuf, float* __restrict__ Bbuf)
{
    int b = blockIdx.x & 63;        // grid 512 = 8 chunks x 64 b
    int c = blockIdx.x >> 6;
    int d = threadIdx.x;            // 128

    float A[SIZEM], Bv[SIZEM];
    #pragma unroll
    for (int m = 0; m < SIZEM; m++) { A[m] = 1.f; Bv[m] = 0.f; }

    const float* wr = w + ((size_t)b * TT + c * CL) * SIZEM;
    const float* er = e + ((size_t)b * TT + c * CL) * DIMS + d;
    const float* ar = a + ((size_t)b * TT + c * CL) * DIMS + d;

    for (int t = 0; t < CL; t++) {
        float ed = er[(size_t)t * DIMS];
        float ad = ar[(size_t)t * DIMS];
        const float* wt = wr + (size_t)t * SIZEM;
        #pragma unroll
        for (int m = 0; m < SIZEM; m++) {
            float wv = wt[m];                       // block-uniform -> s_load
            float t1 = wv * ed;
            A[m]  = fmaf(-A[m], t1, A[m]);          // A *= (1 - t1)
            Bv[m] = fmaf(-Bv[m], t1, fmaf(wv, ad, Bv[m]));
        }
    }
    if (c < NCH - 1) {              // chunk 7's A/B is never read
        float* Ao = Abuf + ((size_t)b * NCH + c) * SIZEM * DIMS + d;
        float* Bo = Bbuf + ((size_t)b * NCH + c) * SIZEM * DIMS + d;
        #pragma unroll
        for (int m = 0; m < SIZEM; m++) {
            Ao[(size_t)m * DIMS] = A[m];
            Bo[(size_t)m * DIMS] = Bv[m];
        }
    }
}

// ---------------- S3: prefix-scan chunk start in-block, then expand ----------------
// Same c*64+b block map as compose: A/B prefix + e/a/w re-reads are same-XCD L2
// hits. Mv/read streams use nontemporal stores so they don't evict that set.
__global__ __launch_bounds__(128) void expand_kernel(
    const float* __restrict__ w, const float* __restrict__ e, const float* __restrict__ a,
    const float* __restrict__ Abuf, const float* __restrict__ Bbuf,
    const float* __restrict__ Mv0,
    float* __restrict__ mv_out,     // [B][201][50][128]
    float* __restrict__ read_out)   // [NROWS][128]
{
    int b = blockIdx.x & 63;        // grid 512 = 8 chunks x 64 b
    int c = blockIdx.x >> 6;
    int d = threadIdx.x;            // 128

    float s[SIZEM];
    #pragma unroll
    for (int m = 0; m < SIZEM; m++) s[m] = Mv0[(size_t)m * DIMS + d];

    for (int cc = 0; cc < c; cc++) {            // c is block-uniform
        const float* Ao = Abuf + ((size_t)b * NCH + cc) * (SIZEM * DIMS) + d;
        const float* Bo = Bbuf + ((size_t)b * NCH + cc) * (SIZEM * DIMS) + d;
        #pragma unroll
        for (int m = 0; m < SIZEM; m++)
            s[m] = fmaf(Ao[(size_t)m * DIMS], s[m], Bo[(size_t)m * DIMS]);
    }

    float* mvb = mv_out + (size_t)b * (TT + 1) * SIZEM * DIMS;
    if (c == 0) {
        #pragma unroll
        for (int m = 0; m < SIZEM; m++)
            __builtin_nontemporal_store(s[m], &mvb[(size_t)m * DIMS + d]);  // Mv[:,0]
    }

    const float* wr = w + ((size_t)b * TT + c * CL) * SIZEM;
    const float* er = e + ((size_t)b * TT + c * CL) * DIMS + d;
    const float* ar = a + ((size_t)b * TT + c * CL) * DIMS + d;
    float*       rr = read_out + ((size_t)b * TT + c * CL) * DIMS + d;

    float ed = er[0];
    float ad = ar[0];
    for (int t = 0; t < CL; t++) {
        // prefetch next step's e/a before issuing this step's stores
        int tn = (t + 1 < CL) ? t + 1 : t;
        float edn = er[(size_t)tn * DIMS];
        float adn = ar[(size_t)tn * DIMS];

        const float* wt = wr + (size_t)t * SIZEM;   // block-uniform row -> s_load
        float* mvt = mvb + (size_t)(c * CL + t + 1) * SIZEM * DIMS + d;
        float pr = 0.f;
        #pragma unroll
        for (int m = 0; m < SIZEM; m++) {
            float wv = wt[m];
            pr = fmaf(wv, s[m], pr);                // read uses pre-update state
            float t1 = wv * ed;
            s[m] = fmaf(-s[m], t1, fmaf(wv, ad, s[m]));
            __builtin_nontemporal_store(s[m], &mvt[(size_t)m * DIMS]);
        }
        __builtin_nontemporal_store(pr, &rr[(size_t)t * DIMS]);
        ed = edn; ad = adn;
    }
}

// ---------------- K5: f = tanh([read,k]@f_W^T + f_b); p = sigmoid(f@p_W^T + p_b) ----------------
__global__ __launch_bounds__(256) void fp_kernel(
    const float* __restrict__ readb, const float* __restrict__ k,
    const float* __restrict__ f_W, const float* __restrict__ f_b,
    const float* __restrict__ p_W, const float* __restrict__ p_b,
    float* __restrict__ p_out)
{
    __shared__ float rk[32][256];    // 32 KB
    __shared__ float pred[4][16];
    int tid = threadIdx.x;
    int o  = tid & 127;
    int rh = tid >> 7;               // rows 0..15 / 16..31
    int r0 = blockIdx.x * 32;        // grid 400

    for (int idx = tid; idx < 32 * 256; idx += 256) {
        int r = idx >> 8, dd = idx & 255;
        size_t row = (size_t)(r0 + r);
        rk[r][dd] = (dd < 128) ? readb[row * 128 + dd] : k[row * 128 + (dd - 128)];
    }
    __syncthreads();

    float acc[16];
    #pragma unroll
    for (int i = 0; i < 16; i++) acc[i] = 0.f;

    const float* wrow = f_W + (size_t)o * 256;
    for (int dd = 0; dd < 256; dd += 4) {
        float4 wv = *(const float4*)(wrow + dd);
        #pragma unroll
        for (int i = 0; i < 16; i++) {
            int r = rh * 16 + i;
            float4 v4 = *(const float4*)(&rk[r][dd]);
            acc[i] = fmaf(v4.x, wv.x, acc[i]);
            acc[i] = fmaf(v4.y, wv.y, acc[i]);
            acc[i] = fmaf(v4.z, wv.z, acc[i]);
            acc[i] = fmaf(v4.w, wv.w, acc[i]);
        }
    }

    int wave = tid >> 6;
    float fb = f_b[o];
    float pw = p_W[o];
    float pb = p_b[0];
    #pragma unroll
    for (int i = 0; i < 16; i++) {
        float fv = tanhf(acc[i] + fb);
        float v = fv * pw;
        #pragma unroll
        for (int off = 32; off >= 1; off >>= 1)
            v += __shfl_xor(v, off);
        if ((tid & 63) == 0) pred[wave][i] = v;
    }
    __syncthreads();
    if (tid < 32) {
        int h = tid >> 4, ri = tid & 15;
        float sum = pred[2 * h][ri] + pred[2 * h + 1][ri];
        p_out[r0 + tid] = 1.f / (1.f + __expf(-(sum + pb)));
    }
}

extern "C" void kernel_launch(void* const* d_in, const int* in_sizes, int n_in,
                              void* d_out, int out_size, void* d_ws, size_t ws_size,
                              hipStream_t stream) {
    const int*   qv      = (const int*)d_in[0];
    const int*   rv      = (const int*)d_in[1];
    const int*   pidv    = (const int*)d_in[2];
    const float* pid_emb = (const float*)d_in[3];
    const float* k_emb   = (const float*)d_in[4];
    const float* v_emb   = (const float*)d_in[5];
    const float* Mk      = (const float*)d_in[6];
    const float* Mv0     = (const float*)d_in[7];
    const float* f_W     = (const float*)d_in[8];
    const float* f_b     = (const float*)d_in[9];
    const float* p_W     = (const float*)d_in[10];
    const float* p_b     = (const float*)d_in[11];
    const float* e_W     = (const float*)d_in[12];
    const float* e_b     = (const float*)d_in[13];
    const float* a_W     = (const float*)d_in[14];
    const float* a_b     = (const float*)d_in[15];

    float* out    = (float*)d_out;
    float* p_out  = out;                 // 12800
    float* mv_out = out + NROWS;         // 64*201*50*128

    float* ws = (float*)d_ws;
    float* k_buf    = ws;                          // 1,638,400
    float* w_buf    = ws +  1638400;               //   640,000
    float* e_buf    = ws +  2278400;               // 1,638,400
    float* a_buf    = ws +  3916800;               // 1,638,400
    float* read_buf = ws +  5555200;               // 1,638,400
    float* A_buf    = ws +  7193600;               // 3,276,800
    float* B_buf    = ws + 10470400;               // 3,276,800  (total 55 MB)

    k_kernel<<<NROWS * 32 / 256, 256, 0, stream>>>(qv, pidv, k_emb, pid_emb, k_buf);
    w_kernel<<<800, 256, 0, stream>>>(k_buf, Mk, w_buf);
    ea_kernel<<<NROWS / 32, 256, 0, stream>>>(qv, rv, pidv, v_emb, pid_emb,
                                              e_W, e_b, a_W, a_b, e_buf, a_buf);
    compose_kernel<<<BB * NCH, 128, 0, stream>>>(w_buf, e_buf, a_buf, A_buf, B_buf);
    expand_kernel<<<BB * NCH, 128, 0, stream>>>(w_buf, e_buf, a_buf, A_buf, B_buf,
                                                Mv0, mv_out, read_buf);
    fp_kernel<<<NROWS / 32, 256, 0, stream>>>(read_buf, k_buf, f_W, f_b, p_W, p_b, p_out);
}